// Round 8
// baseline (350.158 us; speedup 1.0000x reference)
//
#include <hip/hip_runtime.h>
#include <cstddef>

#define N_NODES 100000
#define N_EDGES 1600000
#define NCHUNK16 6250   // N_NODES / 16, exact
#define NBUCK 400
#define BUCK_NODES 250
#define EB_CAP 5000     // capacity per bucket; mean 4000, sigma 63 -> +15 sigma
#define BF_EDGES 4096   // edges per k_bfill block
#define BF_BLOCKS ((N_EDGES + BF_EDGES - 1) / BF_EDGES)   // 391

typedef __attribute__((ext_vector_type(8))) short short8;   // 8 bf16 = 4 VGPRs
typedef __attribute__((ext_vector_type(4))) float f32x4;

__device__ __forceinline__ unsigned pack_bf16x2(float a, float b) {
  unsigned ua = __float_as_uint(a); ua += 0x7FFFu + ((ua >> 16) & 1u);
  unsigned ub = __float_as_uint(b); ub += 0x7FFFu + ((ub >> 16) & 1u);
  return (ua >> 16) | (ub & 0xFFFF0000u);
}

// ====== init: cursors + gsum zero + build fragment-ordered bf16 W buffer ====
// wbuf layout: short8 frag for (kstep ks, ftile T) at [(ks*8+T)*64 + lane]:
// lane(col=L&15, quad=L>>4) holds Wcat[T*16+(L&15)][ks*32+quad*8 .. +8] bf16.
__global__ __launch_bounds__(512) void k_init(int* __restrict__ bucket_cursor,
                                              float* __restrict__ gsum,
                                              const float* __restrict__ W2_rel,
                                              const float* __restrict__ W2_root,
                                              unsigned* __restrict__ wbuf) {
  int t = threadIdx.x;
  if (t < NBUCK) bucket_cursor[t] = t * EB_CAP;
  if (t < 128) gsum[t] = 0.0f;
#pragma unroll
  for (int i = 0; i < 8; ++i) {
    int e = t + i * 512;                    // 0..4095
    int L = e & 63, T = (e >> 6) & 7, K0 = e >> 9;
    int f = T * 16 + (L & 15);
    int k0 = K0 * 32 + ((L >> 4) << 3);     // 8-aligned; never crosses 128
    const float* wsrc = (k0 < 128) ? (W2_rel + f * 128 + k0)
                                   : (W2_root + f * 128 + (k0 - 128));
    float4 w0 = *(const float4*)(wsrc);
    float4 w1 = *(const float4*)(wsrc + 4);
    unsigned* d = wbuf + e * 4;
    d[0] = pack_bf16x2(w0.x, w0.y);
    d[1] = pack_bf16x2(w0.z, w0.w);
    d[2] = pack_bf16x2(w1.x, w1.y);
    d[3] = pack_bf16x2(w1.z, w1.w);
  }
}

// ============ CSR build pass 1: bucket-scatter edges (register-staged) ======
__global__ __launch_bounds__(256) void k_bfill(const int* __restrict__ src,
                                               const int* __restrict__ dst,
                                               int* __restrict__ bucket_cursor,
                                               uint2* __restrict__ ebuf) {
  __shared__ int lh[NBUCK];
  __shared__ int sub_base[NBUCK];
  __shared__ int cur[NBUCK];
  int t = threadIdx.x;
  for (int b = t; b < NBUCK; b += 256) { lh[b] = 0; cur[b] = 0; }
  __syncthreads();
  int e0 = blockIdx.x * BF_EDGES;
  uint2 p[16];
#pragma unroll
  for (int i = 0; i < 16; ++i) {
    int e = e0 + i * 256 + t;
    p[i] = make_uint2(0u, 0xFFFFFFFFu);
    if (e < N_EDGES) {
      p[i] = make_uint2((unsigned)src[e], (unsigned)dst[e]);
      atomicAdd(&lh[p[i].y / BUCK_NODES], 1);
    }
  }
  __syncthreads();
  for (int b = t; b < NBUCK; b += 256)
    sub_base[b] = (lh[b] > 0) ? atomicAdd(&bucket_cursor[b], lh[b]) : 0;
  __syncthreads();
#pragma unroll
  for (int i = 0; i < 16; ++i) {
    if (p[i].y != 0xFFFFFFFFu) {
      int b = p[i].y / BUCK_NODES;
      int pos = sub_base[b] + atomicAdd(&cur[b], 1);
      if (pos < (b + 1) * EB_CAP) ebuf[pos] = p[i];  // overflow guard (15 sigma)
    }
  }
}

// ============ CSR build pass 2: one block per bucket ============
__global__ __launch_bounds__(256) void k_fill2(
    const uint2* __restrict__ ebuf, const int* __restrict__ bucket_cursor,
    int* __restrict__ row_start, int* __restrict__ row_end,
    int* __restrict__ csr_src) {
  __shared__ int cnt[256];
  __shared__ int start[256];
  __shared__ int partial[8];
  int t = threadIdx.x;
  int b = blockIdx.x;
  int base = b * EB_CAP;
  int nb = bucket_cursor[b] - base;
  int n0 = b * BUCK_NODES;
  cnt[t] = 0;
  __syncthreads();
  for (int i = t; i < nb; i += 256) {
    atomicAdd(&cnt[ebuf[base + i].y - n0], 1);
  }
  __syncthreads();
  if (t < 8) {
    int s = 0;
#pragma unroll
    for (int j = 0; j < 32; ++j) { start[t * 32 + j] = s; s += cnt[t * 32 + j]; }
    partial[t] = s;
  }
  __syncthreads();
  if (t == 0) {
    int s = 0;
#pragma unroll
    for (int j = 0; j < 8; ++j) { int tmp = partial[j]; partial[j] = s; s += tmp; }
  }
  __syncthreads();
  if (t < 8) {
    int off = partial[t];
#pragma unroll
    for (int j = 0; j < 32; ++j) start[t * 32 + j] += off;
  }
  __syncthreads();
  if (t < BUCK_NODES) {
    row_start[n0 + t] = base + start[t];
    cnt[t] = start[t];    // reuse as cursor
  }
  __syncthreads();
  for (int i = t; i < nb; i += 256) {
    uint2 e = ebuf[base + i];
    int p = atomicAdd(&cnt[e.y - n0], 1);
    csr_src[base + p] = (int)e.x;
  }
  __syncthreads();
  if (t < BUCK_NODES) row_end[n0 + t] = base + cnt[t];
}

// ============ layer 1: pull-aggregate x (Fin=4), thread per node ============
__global__ __launch_bounds__(256) void k_pull4(
    const float* __restrict__ x, const int* __restrict__ row_start,
    const int* __restrict__ row_end, const int* __restrict__ csr_src,
    float* __restrict__ agg1) {
  int n = blockIdx.x * 256 + threadIdx.x;
  if (n >= N_NODES) return;
  int rs = row_start[n], re = row_end[n];
  float4 acc = make_float4(0.f, 0.f, 0.f, 0.f);
  for (int i = rs; i < re; ++i) {
    int s = csr_src[i];
    float4 v = *(const float4*)(x + (size_t)s * 4);
    acc.x += v.x; acc.y += v.y; acc.z += v.z; acc.w += v.w;
  }
  *(float4*)(agg1 + (size_t)n * 4) = acc;
}

// ====== layer 1 dense: h1 = relu(...) computed fp32, stored bf16 rows ======
__global__ __launch_bounds__(256) void k_layer1(
    const float* __restrict__ x, const float* __restrict__ agg1,
    const float* __restrict__ W1_rel, const float* __restrict__ b1,
    const float* __restrict__ W1_root, unsigned* __restrict__ h1b) {
  int tid = blockIdx.x * 256 + threadIdx.x;
  if (tid >= N_NODES * 64) return;
  int node = tid >> 6;
  int f = (tid & 63) * 2;
  float4 a  = *(const float4*)(agg1 + node * 4);
  float4 xv = *(const float4*)(x + node * 4);
  float4 wr0 = *(const float4*)(W1_rel + f * 4);
  float4 wo0 = *(const float4*)(W1_root + f * 4);
  float4 wr1 = *(const float4*)(W1_rel + (f + 1) * 4);
  float4 wo1 = *(const float4*)(W1_root + (f + 1) * 4);
  float v0 = b1[f]
      + a.x * wr0.x + a.y * wr0.y + a.z * wr0.z + a.w * wr0.w
      + xv.x * wo0.x + xv.y * wo0.y + xv.z * wo0.z + xv.w * wo0.w;
  float v1 = b1[f + 1]
      + a.x * wr1.x + a.y * wr1.y + a.z * wr1.z + a.w * wr1.w
      + xv.x * wo1.x + xv.y * wo1.y + xv.z * wo1.z + xv.w * wo1.w;
  h1b[tid] = pack_bf16x2(fmaxf(v0, 0.f), fmaxf(v1, 0.f));
}

// ====== fused layer-2: aggregate 16-node tile -> LDS A-frag -> MFMA -> pool ==
// One wave per 16-node tile (6250 tiles). Gather identical to old k_pull128
// (4-deep, proven); result transposed into MFMA A-layout via wave-private LDS
// (stride 68 dwords: write side conflict-free, read side mild). Weights come
// fragment-ordered from global wbuf (L1/L2-resident, no block LDS staging).
__global__ __launch_bounds__(256) void k_agg_gemm_pool(
    const unsigned* __restrict__ h1b, const int* __restrict__ row_start,
    const int* __restrict__ row_end, const int* __restrict__ csr_src,
    const unsigned* __restrict__ wbuf_u, const float* __restrict__ b2,
    float* __restrict__ gsum) {
  __shared__ unsigned atile[4][16 * 68];   // 4 waves x 4352 B = 17.4 KB
  __shared__ float lgs[128];
  int t = threadIdx.x;
  if (t < 128) lgs[t] = 0.0f;
  __syncthreads();

  int lane = t & 63;
  int wv = t >> 6;
  int gw = blockIdx.x * 4 + wv;
  int lrow = lane & 15;
  int quad = lane >> 4;
  const short8* wbuf = (const short8*)wbuf_u;

  float bias[8];
#pragma unroll
  for (int tt = 0; tt < 8; ++tt) bias[tt] = b2[tt * 16 + lrow];
  float csum[8] = {0.f, 0.f, 0.f, 0.f, 0.f, 0.f, 0.f, 0.f};

  if (gw < NCHUNK16) {
    int tb = gw * 16;
    unsigned* at = atile[wv];

    // ---- aggregate the 16 nodes of this tile (wave-cooperative per node) ----
    for (int nd = 0; nd < 16; ++nd) {
      int n = tb + nd;
      int rs = row_start[n], re = row_end[n];
      float ax = 0.f, ay = 0.f;
      for (int chunk = rs; chunk < re; chunk += 64) {
        int nv = min(64, re - chunk);
        int sv = (chunk + lane < re) ? csr_src[chunk + lane] : 0;
        int jj = 0;
        for (; jj + 4 <= nv; jj += 4) {
          int s0 = __shfl(sv, jj);
          int s1 = __shfl(sv, jj + 1);
          int s2 = __shfl(sv, jj + 2);
          int s3 = __shfl(sv, jj + 3);
          unsigned u0 = h1b[(size_t)s0 * 64 + lane];
          unsigned u1 = h1b[(size_t)s1 * 64 + lane];
          unsigned u2 = h1b[(size_t)s2 * 64 + lane];
          unsigned u3 = h1b[(size_t)s3 * 64 + lane];
          ax += __uint_as_float(u0 << 16) + __uint_as_float(u1 << 16)
              + __uint_as_float(u2 << 16) + __uint_as_float(u3 << 16);
          ay += __uint_as_float(u0 & 0xFFFF0000u) + __uint_as_float(u1 & 0xFFFF0000u)
              + __uint_as_float(u2 & 0xFFFF0000u) + __uint_as_float(u3 & 0xFFFF0000u);
        }
        for (; jj < nv; ++jj) {
          int s0 = __shfl(sv, jj);
          unsigned u0 = h1b[(size_t)s0 * 64 + lane];
          ax += __uint_as_float(u0 << 16);
          ay += __uint_as_float(u0 & 0xFFFF0000u);
        }
      }
      at[nd * 68 + lane] = pack_bf16x2(ax, ay);  // features (2*lane, 2*lane+1)
    }

    // ---- MFMA: K 0..127 from LDS tile (agg), 128..255 from h1b (root) ----
    f32x4 acc[8];
#pragma unroll
    for (int tt = 0; tt < 8; ++tt) acc[tt] = (f32x4){0.f, 0.f, 0.f, 0.f};

#pragma unroll
    for (int ks = 0; ks < 4; ++ks) {
      short8 afr = *(const short8*)&at[lrow * 68 + ks * 16 + quad * 4];
#pragma unroll
      for (int tt = 0; tt < 8; ++tt) {
        short8 bfr = wbuf[(ks * 8 + tt) * 64 + lane];
        acc[tt] = __builtin_amdgcn_mfma_f32_16x16x32_bf16(afr, bfr, acc[tt], 0, 0, 0);
      }
    }
    const unsigned short* h1s = (const unsigned short*)h1b;
#pragma unroll
    for (int ks = 4; ks < 8; ++ks) {
      short8 afr = *(const short8*)(h1s + (size_t)(tb + lrow) * 128
                                    + (ks - 4) * 32 + quad * 8);
#pragma unroll
      for (int tt = 0; tt < 8; ++tt) {
        short8 bfr = wbuf[(ks * 8 + tt) * 64 + lane];
        acc[tt] = __builtin_amdgcn_mfma_f32_16x16x32_bf16(afr, bfr, acc[tt], 0, 0, 0);
      }
    }

    // ---- epilogue: relu + column-sum over the 16 rows ----
#pragma unroll
    for (int tt = 0; tt < 8; ++tt) {
      f32x4 v = acc[tt];
      float s = fmaxf(v.x + bias[tt], 0.f) + fmaxf(v.y + bias[tt], 0.f)
              + fmaxf(v.z + bias[tt], 0.f) + fmaxf(v.w + bias[tt], 0.f);
      s += __shfl_xor(s, 16);
      s += __shfl_xor(s, 32);
      csum[tt] += s;
    }
  }

  // block-level reduction, then one global atomic per element per block
  if (lane < 16) {
#pragma unroll
    for (int tt = 0; tt < 8; ++tt) atomicAdd(&lgs[tt * 16 + lane], csum[tt]);
  }
  __syncthreads();
  if (t < 128) atomicAdd(&gsum[t], lgs[t]);
}

// ============ head: out = (gsum/N) @ Wlin.T + blin ============
__global__ void k_final(const float* __restrict__ gsum, const float* __restrict__ Wlin,
                        const float* __restrict__ blin, float* __restrict__ out) {
  int lane = threadIdx.x;  // 64 threads
  float g0 = gsum[lane];
  float g1 = gsum[lane + 64];
  float s0 = g0 * Wlin[lane]       + g1 * Wlin[lane + 64];
  float s1 = g0 * Wlin[128 + lane] + g1 * Wlin[192 + lane];
#pragma unroll
  for (int off = 32; off > 0; off >>= 1) {
    s0 += __shfl_down(s0, off);
    s1 += __shfl_down(s1, off);
  }
  if (lane == 0) {
    const float inv = 1.0f / (float)N_NODES;
    out[0] = s0 * inv + blin[0];
    out[1] = s1 * inv + blin[1];
  }
}

extern "C" void kernel_launch(void* const* d_in, const int* in_sizes, int n_in,
                              void* d_out, int out_size, void* d_ws, size_t ws_size,
                              hipStream_t stream) {
  const float* x       = (const float*)d_in[0];
  const int*   ei      = (const int*)d_in[1];
  const float* W1_rel  = (const float*)d_in[2];
  const float* b1      = (const float*)d_in[3];
  const float* W1_root = (const float*)d_in[4];
  const float* W2_rel  = (const float*)d_in[5];
  const float* b2      = (const float*)d_in[6];
  const float* W2_root = (const float*)d_in[7];
  const float* Wlin    = (const float*)d_in[8];
  const float* blin    = (const float*)d_in[9];
  const int* src = ei;            // edge_index[0]
  const int* dst = ei + N_EDGES;  // edge_index[1]
  float* out = (float*)d_out;

  // workspace layout (bytes):
  //   row_start     @0          : 400,000
  //   row_end       @400,000    : 400,000
  //   bucket_cursor @800,000    : 1,600
  //   gsum          @801,600    : 512
  //   wbuf          @802,112    : 65,536     -> 867,648
  //   csr_src       @867,648    : 8,000,000  -> 8,867,648
  //   ebuf (uint2)  @8,867,648  : 16,000,000 -> 24,867,648
  //   h1b           @24,867,648 : 25,600,000 -> 50,467,648
  //   agg1          @50,467,648 : 1,600,000  -> 52,067,648
  char* ws = (char*)d_ws;
  int*      row_start     = (int*)(ws);
  int*      row_end       = (int*)(ws + 400000);
  int*      bucket_cursor = (int*)(ws + 800000);
  float*    gsum          = (float*)(ws + 801600);
  unsigned* wbuf          = (unsigned*)(ws + 802112);
  int*      csr_src       = (int*)(ws + 867648);
  uint2*    ebuf          = (uint2*)(ws + 8867648);
  unsigned* h1b           = (unsigned*)(ws + 24867648);
  float*    agg1          = (float*)(ws + 50467648);

  k_init <<<1, 512, 0, stream>>>(bucket_cursor, gsum, W2_rel, W2_root, wbuf);
  k_bfill<<<BF_BLOCKS, 256, 0, stream>>>(src, dst, bucket_cursor, ebuf);
  k_fill2<<<NBUCK, 256, 0, stream>>>(ebuf, bucket_cursor, row_start, row_end, csr_src);
  k_pull4<<<(N_NODES + 255) / 256, 256, 0, stream>>>(x, row_start, row_end, csr_src, agg1);
  k_layer1<<<(N_NODES * 64 + 255) / 256, 256, 0, stream>>>(x, agg1, W1_rel, b1, W1_root, h1b);
  k_agg_gemm_pool<<<(NCHUNK16 + 3) / 4, 256, 0, stream>>>(h1b, row_start, row_end,
                                                          csr_src, wbuf, b2, gsum);
  k_final<<<1, 64, 0, stream>>>(gsum, Wlin, blin, out);
}

// Round 9
// 256.059 us; speedup vs baseline: 1.3675x; 1.3675x over previous
//
#include <hip/hip_runtime.h>
#include <cstddef>

#define N_NODES 100000
#define N_EDGES 1600000
#define NCHUNK32 3125   // N_NODES / 32, exact
#define NBUCK 800
#define BUCK_NODES 125
#define EB_CAP 2500     // mean 2000, sigma ~45 -> +11 sigma
#define BF_EDGES 4096
#define BF_BLOCKS ((N_EDGES + BF_EDGES - 1) / BF_EDGES)   // 391

typedef __attribute__((ext_vector_type(8))) short short8;   // 8 bf16 = 4 VGPRs
typedef __attribute__((ext_vector_type(4))) float f32x4;

__device__ __forceinline__ unsigned pack_bf16x2(float a, float b) {
  unsigned ua = __float_as_uint(a); ua += 0x7FFFu + ((ua >> 16) & 1u);
  unsigned ub = __float_as_uint(b); ub += 0x7FFFu + ((ub >> 16) & 1u);
  return (ua >> 16) | (ub & 0xFFFF0000u);
}

// ============ init: bucket cursors + gsum ============
__global__ __launch_bounds__(512) void k_init(int* __restrict__ bucket_cursor,
                                              float* __restrict__ gsum) {
  int t = threadIdx.x;
  for (int b = t; b < NBUCK; b += 512) bucket_cursor[b] = b * EB_CAP;
  if (t < 128) gsum[t] = 0.0f;
}

// ============ CSR build pass 1: bucket-scatter packed edges ============
// packed edge = (dst_local << 17) | src  (dst_local < 125, src < 2^17)
__global__ __launch_bounds__(256) void k_bfill(const int* __restrict__ src,
                                               const int* __restrict__ dst,
                                               int* __restrict__ bucket_cursor,
                                               unsigned* __restrict__ ebuf) {
  __shared__ int lh[NBUCK];
  __shared__ int sub_base[NBUCK];
  __shared__ int cur[NBUCK];
  int t = threadIdx.x;
  for (int b = t; b < NBUCK; b += 256) { lh[b] = 0; cur[b] = 0; }
  __syncthreads();
  int e0 = blockIdx.x * BF_EDGES;
  unsigned pk[16];
  int bk[16];
#pragma unroll
  for (int i = 0; i < 16; ++i) {
    int e = e0 + i * 256 + t;
    bk[i] = -1;
    if (e < N_EDGES) {
      int d = dst[e];
      int b = d / BUCK_NODES;
      int dloc = d - b * BUCK_NODES;
      bk[i] = b;
      pk[i] = ((unsigned)dloc << 17) | (unsigned)src[e];
      atomicAdd(&lh[b], 1);
    }
  }
  __syncthreads();
  for (int b = t; b < NBUCK; b += 256)
    sub_base[b] = (lh[b] > 0) ? atomicAdd(&bucket_cursor[b], lh[b]) : 0;
  __syncthreads();
#pragma unroll
  for (int i = 0; i < 16; ++i) {
    if (bk[i] >= 0) {
      int pos = sub_base[bk[i]] + atomicAdd(&cur[bk[i]], 1);
      if (pos < (bk[i] + 1) * EB_CAP) ebuf[pos] = pk[i];  // +11 sigma guard
    }
  }
}

// ====== CSR build pass 2 + layer-1 (fused): one block per bucket ======
// Builds csr_src/row_start/row_end; aggregates x into LDS (float atomics);
// computes h1 = relu(agg1@W1_rel.T + b1 + x@W1_root.T), stores bf16 rows.
__global__ __launch_bounds__(256) void k_fill2(
    const unsigned* __restrict__ ebuf, const int* __restrict__ bucket_cursor,
    const float* __restrict__ x, const float* __restrict__ W1_rel,
    const float* __restrict__ b1, const float* __restrict__ W1_root,
    int* __restrict__ row_start, int* __restrict__ row_end,
    int* __restrict__ csr_src, unsigned* __restrict__ h1b) {
  __shared__ int cnt[128];
  __shared__ int start[128];
  __shared__ int partial[4];
  __shared__ float sagg[BUCK_NODES * 4];
  __shared__ float sx[BUCK_NODES * 4];
  __shared__ float sWa[8 * 128];   // SoA: sWa[j*128+f], j<4 = W1_rel col j, j>=4 = W1_root
  __shared__ float sb1[128];
  int t = threadIdx.x;
  int b = blockIdx.x;
  int base = b * EB_CAP;
  int nb = bucket_cursor[b] - base;
  int n0 = b * BUCK_NODES;

  if (t < 128) {
    cnt[t] = 0;
    float4 wr = *(const float4*)(W1_rel + t * 4);
    float4 wo = *(const float4*)(W1_root + t * 4);
    sWa[0 * 128 + t] = wr.x; sWa[1 * 128 + t] = wr.y;
    sWa[2 * 128 + t] = wr.z; sWa[3 * 128 + t] = wr.w;
    sWa[4 * 128 + t] = wo.x; sWa[5 * 128 + t] = wo.y;
    sWa[6 * 128 + t] = wo.z; sWa[7 * 128 + t] = wo.w;
    sb1[t] = b1[t];
  }
  for (int i = t; i < BUCK_NODES * 4; i += 256) sagg[i] = 0.0f;
  __syncthreads();

  // degree histogram
  for (int i = t; i < nb; i += 256) atomicAdd(&cnt[ebuf[base + i] >> 17], 1);
  __syncthreads();
  // exclusive scan of 128
  if (t < 4) {
    int s = 0;
#pragma unroll
    for (int j = 0; j < 32; ++j) { start[t * 32 + j] = s; s += cnt[t * 32 + j]; }
    partial[t] = s;
  }
  __syncthreads();
  if (t == 0) {
    int s = 0;
#pragma unroll
    for (int j = 0; j < 4; ++j) { int tmp = partial[j]; partial[j] = s; s += tmp; }
  }
  __syncthreads();
  if (t < 4) {
    int off = partial[t];
#pragma unroll
    for (int j = 0; j < 32; ++j) start[t * 32 + j] += off;
  }
  __syncthreads();
  if (t < BUCK_NODES) {
    row_start[n0 + t] = base + start[t];
    cnt[t] = start[t];    // reuse as cursor
    *(float4*)&sx[t * 4] = *(const float4*)(x + (size_t)(n0 + t) * 4);
  }
  __syncthreads();
  // scatter csr + aggregate x into LDS in one pass
  for (int i = t; i < nb; i += 256) {
    unsigned e = ebuf[base + i];
    int dloc = e >> 17;
    int s = (int)(e & 0x1FFFFu);
    int p = atomicAdd(&cnt[dloc], 1);
    csr_src[base + p] = s;
    float4 v = *(const float4*)(x + (size_t)s * 4);
    atomicAdd(&sagg[dloc * 4 + 0], v.x);
    atomicAdd(&sagg[dloc * 4 + 1], v.y);
    atomicAdd(&sagg[dloc * 4 + 2], v.z);
    atomicAdd(&sagg[dloc * 4 + 3], v.w);
  }
  __syncthreads();
  if (t < BUCK_NODES) row_end[n0 + t] = base + cnt[t];

  // layer-1 dense for this bucket's nodes: 125 nodes x 64 feature-pairs
  for (int it = t; it < BUCK_NODES * 64; it += 256) {
    int nd = it >> 6;
    int fp = it & 63;
    int f = fp * 2;
    float4 a  = *(float4*)&sagg[nd * 4];
    float4 xv = *(float4*)&sx[nd * 4];
    float v0 = sb1[f]
        + a.x  * sWa[0 * 128 + f] + a.y  * sWa[1 * 128 + f]
        + a.z  * sWa[2 * 128 + f] + a.w  * sWa[3 * 128 + f]
        + xv.x * sWa[4 * 128 + f] + xv.y * sWa[5 * 128 + f]
        + xv.z * sWa[6 * 128 + f] + xv.w * sWa[7 * 128 + f];
    int f1 = f + 1;
    float v1 = sb1[f1]
        + a.x  * sWa[0 * 128 + f1] + a.y  * sWa[1 * 128 + f1]
        + a.z  * sWa[2 * 128 + f1] + a.w  * sWa[3 * 128 + f1]
        + xv.x * sWa[4 * 128 + f1] + xv.y * sWa[5 * 128 + f1]
        + xv.z * sWa[6 * 128 + f1] + xv.w * sWa[7 * 128 + f1];
    h1b[(size_t)(n0 + nd) * 64 + fp] = pack_bf16x2(fmaxf(v0, 0.f), fmaxf(v1, 0.f));
  }
}

// ============ layer 2 aggregate: pull bf16 h1 rows, one WAVE per node ======
// R6-proven version: 4-deep gather unroll (8-deep regressed: L2 thrash).
__global__ __launch_bounds__(256) void k_pull128(
    const unsigned* __restrict__ h1b, const int* __restrict__ row_start,
    const int* __restrict__ row_end, const int* __restrict__ csr_src,
    unsigned* __restrict__ agg2b) {
  int w = (blockIdx.x * 256 + threadIdx.x) >> 6;
  if (w >= N_NODES) return;
  int lane = threadIdx.x & 63;
  int rs = row_start[w], re = row_end[w];
  float ax = 0.f, ay = 0.f;
  for (int chunk = rs; chunk < re; chunk += 64) {
    int nv = min(64, re - chunk);
    int sv = (chunk + lane < re) ? csr_src[chunk + lane] : 0;
    int j = 0;
    for (; j + 4 <= nv; j += 4) {
      int s0 = __shfl(sv, j);
      int s1 = __shfl(sv, j + 1);
      int s2 = __shfl(sv, j + 2);
      int s3 = __shfl(sv, j + 3);
      unsigned u0 = h1b[(size_t)s0 * 64 + lane];
      unsigned u1 = h1b[(size_t)s1 * 64 + lane];
      unsigned u2 = h1b[(size_t)s2 * 64 + lane];
      unsigned u3 = h1b[(size_t)s3 * 64 + lane];
      ax += __uint_as_float(u0 << 16) + __uint_as_float(u1 << 16)
          + __uint_as_float(u2 << 16) + __uint_as_float(u3 << 16);
      ay += __uint_as_float(u0 & 0xFFFF0000u) + __uint_as_float(u1 & 0xFFFF0000u)
          + __uint_as_float(u2 & 0xFFFF0000u) + __uint_as_float(u3 & 0xFFFF0000u);
    }
    for (; j < nv; ++j) {
      int s0 = __shfl(sv, j);
      unsigned u0 = h1b[(size_t)s0 * 64 + lane];
      ax += __uint_as_float(u0 << 16);
      ay += __uint_as_float(u0 & 0xFFFF0000u);
    }
  }
  agg2b[(size_t)w * 64 + lane] = pack_bf16x2(ax, ay);
}

// ====== layer 2 dense + pool: MFMA GEMM, 32-node waves (M=2 tiles) ======
// acc 64 regs/thread -> higher occupancy; 3125 waves (vs 1563 at M=4).
__global__ __launch_bounds__(256) void k_gemm_pool(
    const unsigned* __restrict__ agg2b_u, const unsigned* __restrict__ h1b_u,
    const float* __restrict__ W2_rel, const float* __restrict__ b2,
    const float* __restrict__ W2_root, float* __restrict__ gsum) {
  __shared__ unsigned short lds_w[32768];  // 64 KB: [8 ksteps][8 ftiles][64 lanes][8 bf16]
  __shared__ float lgs[128];
  int t = threadIdx.x;
  if (t < 128) lgs[t] = 0.0f;

#pragma unroll
  for (int i = 0; i < 16; ++i) {
    int e = t + i * 256;                    // 0..4095
    int L = e & 63, T = (e >> 6) & 7, K0 = e >> 9;
    int f = T * 16 + (L & 15);
    int k0 = K0 * 32 + ((L >> 4) << 3);
    const float* wsrc = (k0 < 128) ? (W2_rel + f * 128 + k0)
                                   : (W2_root + f * 128 + (k0 - 128));
    float4 w0 = *(const float4*)(wsrc);
    float4 w1 = *(const float4*)(wsrc + 4);
    unsigned* d = (unsigned*)&lds_w[e * 8];
    d[0] = pack_bf16x2(w0.x, w0.y);
    d[1] = pack_bf16x2(w0.z, w0.w);
    d[2] = pack_bf16x2(w1.x, w1.y);
    d[3] = pack_bf16x2(w1.z, w1.w);
  }
  __syncthreads();

  int lane = t & 63;
  int gw = blockIdx.x * 4 + (t >> 6);
  int lrow = lane & 15;
  int quad = lane >> 4;
  const unsigned short* agg2b = (const unsigned short*)agg2b_u;
  const unsigned short* h1b   = (const unsigned short*)h1b_u;

  float bias[8];
#pragma unroll
  for (int tt = 0; tt < 8; ++tt) bias[tt] = b2[tt * 16 + lrow];
  float csum[8] = {0.f, 0.f, 0.f, 0.f, 0.f, 0.f, 0.f, 0.f};

  if (gw < NCHUNK32) {
    int mbase = gw * 32;   // N_NODES % 32 == 0: no clamp, no gating

    f32x4 acc[2][8];
#pragma unroll
    for (int mt = 0; mt < 2; ++mt)
#pragma unroll
      for (int tt = 0; tt < 8; ++tt) acc[mt][tt] = (f32x4){0.f, 0.f, 0.f, 0.f};

#pragma unroll
    for (int ks = 0; ks < 8; ++ks) {
      const unsigned short* abase = (ks < 4)
          ? (agg2b + ks * 32 + quad * 8)
          : (h1b + (ks - 4) * 32 + quad * 8);
      short8 afr[2];
#pragma unroll
      for (int mt = 0; mt < 2; ++mt)
        afr[mt] = *(const short8*)(abase + (size_t)(mbase + mt * 16 + lrow) * 128);
      const short8* wl = (const short8*)lds_w;
      short8 bfr[8];
#pragma unroll
      for (int tt = 0; tt < 8; ++tt) bfr[tt] = wl[(ks * 8 + tt) * 64 + lane];
#pragma unroll
      for (int mt = 0; mt < 2; ++mt)
#pragma unroll
        for (int tt = 0; tt < 8; ++tt)
          acc[mt][tt] = __builtin_amdgcn_mfma_f32_16x16x32_bf16(
              afr[mt], bfr[tt], acc[mt][tt], 0, 0, 0);
    }

#pragma unroll
    for (int mt = 0; mt < 2; ++mt) {
#pragma unroll
      for (int tt = 0; tt < 8; ++tt) {
        f32x4 v = acc[mt][tt];
        float s = fmaxf(v.x + bias[tt], 0.f) + fmaxf(v.y + bias[tt], 0.f)
                + fmaxf(v.z + bias[tt], 0.f) + fmaxf(v.w + bias[tt], 0.f);
        s += __shfl_xor(s, 16);
        s += __shfl_xor(s, 32);
        csum[tt] += s;
      }
    }
  }
  // block-level LDS reduction, then 128 global atomics per block
  if (lane < 16) {
#pragma unroll
    for (int tt = 0; tt < 8; ++tt) atomicAdd(&lgs[tt * 16 + lane], csum[tt]);
  }
  __syncthreads();
  if (t < 128) atomicAdd(&gsum[t], lgs[t]);
}

// ============ head: out = (gsum/N) @ Wlin.T + blin ============
__global__ void k_final(const float* __restrict__ gsum, const float* __restrict__ Wlin,
                        const float* __restrict__ blin, float* __restrict__ out) {
  int lane = threadIdx.x;  // 64 threads
  float g0 = gsum[lane];
  float g1 = gsum[lane + 64];
  float s0 = g0 * Wlin[lane]       + g1 * Wlin[lane + 64];
  float s1 = g0 * Wlin[128 + lane] + g1 * Wlin[192 + lane];
#pragma unroll
  for (int off = 32; off > 0; off >>= 1) {
    s0 += __shfl_down(s0, off);
    s1 += __shfl_down(s1, off);
  }
  if (lane == 0) {
    const float inv = 1.0f / (float)N_NODES;
    out[0] = s0 * inv + blin[0];
    out[1] = s1 * inv + blin[1];
  }
}

extern "C" void kernel_launch(void* const* d_in, const int* in_sizes, int n_in,
                              void* d_out, int out_size, void* d_ws, size_t ws_size,
                              hipStream_t stream) {
  const float* x       = (const float*)d_in[0];
  const int*   ei      = (const int*)d_in[1];
  const float* W1_rel  = (const float*)d_in[2];
  const float* b1      = (const float*)d_in[3];
  const float* W1_root = (const float*)d_in[4];
  const float* W2_rel  = (const float*)d_in[5];
  const float* b2      = (const float*)d_in[6];
  const float* W2_root = (const float*)d_in[7];
  const float* Wlin    = (const float*)d_in[8];
  const float* blin    = (const float*)d_in[9];
  const int* src = ei;            // edge_index[0]
  const int* dst = ei + N_EDGES;  // edge_index[1]
  float* out = (float*)d_out;

  // workspace layout (bytes):
  //   row_start     @0          : 400,000
  //   row_end       @400,000    : 400,000
  //   bucket_cursor @800,000    : 3,200
  //   gsum          @803,200    : 512
  //   csr_src       @803,712    : 8,000,000  -> 8,803,712
  //   ebuf (uint)   @8,803,712  : 8,000,000  -> 16,803,712
  //   h1b           @16,803,712 : 25,600,000 -> 42,403,712
  //   agg2b         @42,403,712 : 25,600,000 -> 68,003,712
  char* ws = (char*)d_ws;
  int*      row_start     = (int*)(ws);
  int*      row_end       = (int*)(ws + 400000);
  int*      bucket_cursor = (int*)(ws + 800000);
  float*    gsum          = (float*)(ws + 803200);
  int*      csr_src       = (int*)(ws + 803712);
  unsigned* ebuf          = (unsigned*)(ws + 8803712);
  unsigned* h1b           = (unsigned*)(ws + 16803712);
  unsigned* agg2b         = (unsigned*)(ws + 42403712);

  k_init <<<1, 512, 0, stream>>>(bucket_cursor, gsum);
  k_bfill<<<BF_BLOCKS, 256, 0, stream>>>(src, dst, bucket_cursor, ebuf);
  k_fill2<<<NBUCK, 256, 0, stream>>>(ebuf, bucket_cursor, x, W1_rel, b1, W1_root,
                                     row_start, row_end, csr_src, h1b);
  k_pull128<<<(N_NODES * 64 + 255) / 256, 256, 0, stream>>>(h1b, row_start, row_end,
                                                            csr_src, agg2b);
  k_gemm_pool<<<(NCHUNK32 + 3) / 4, 256, 0, stream>>>(agg2b, h1b, W2_rel, b2, W2_root, gsum);
  k_final<<<1, 64, 0, stream>>>(gsum, Wlin, blin, out);
}

// Round 10
// 249.990 us; speedup vs baseline: 1.4007x; 1.0243x over previous
//
#include <hip/hip_runtime.h>
#include <cstddef>

#define N_NODES 100000
#define N_EDGES 1600000
#define NCHUNK32 3125   // N_NODES / 32, exact
#define NBUCK 800
#define BUCK_NODES 125
#define EB_CAP 2500     // mean 2000, sigma ~45 -> +11 sigma
#define BF_EDGES 4096
#define BF_BLOCKS ((N_EDGES + BF_EDGES - 1) / BF_EDGES)   // 391

typedef __attribute__((ext_vector_type(8))) short short8;   // 8 bf16 = 4 VGPRs
typedef __attribute__((ext_vector_type(4))) float f32x4;
typedef __attribute__((ext_vector_type(2))) float f32x2;

__device__ __forceinline__ unsigned pack_bf16x2(float a, float b) {
  unsigned ua = __float_as_uint(a); ua += 0x7FFFu + ((ua >> 16) & 1u);
  unsigned ub = __float_as_uint(b); ub += 0x7FFFu + ((ub >> 16) & 1u);
  return (ua >> 16) | (ub & 0xFFFF0000u);
}

// ====== init: cursors + gsum + fragment-ordered bf16 W2 buffer (global) ====
// wbuf layout: short8 frag for (kstep ks, ftile T) at [(ks*8+T)*64 + lane]:
// lane(col=L&15, quad=L>>4) holds Wcat[T*16+(L&15)][ks*32+quad*8 .. +8] bf16.
__global__ __launch_bounds__(512) void k_init(int* __restrict__ bucket_cursor,
                                              float* __restrict__ gsum,
                                              const float* __restrict__ W2_rel,
                                              const float* __restrict__ W2_root,
                                              unsigned* __restrict__ wbuf) {
  int t = threadIdx.x;
  for (int b = t; b < NBUCK; b += 512) bucket_cursor[b] = b * EB_CAP;
  if (t < 128) gsum[t] = 0.0f;
#pragma unroll
  for (int i = 0; i < 8; ++i) {
    int e = t + i * 512;                    // 0..4095
    int L = e & 63, T = (e >> 6) & 7, K0 = e >> 9;
    int f = T * 16 + (L & 15);
    int k0 = K0 * 32 + ((L >> 4) << 3);     // 8-aligned; never crosses 128
    const float* wsrc = (k0 < 128) ? (W2_rel + f * 128 + k0)
                                   : (W2_root + f * 128 + (k0 - 128));
    float4 w0 = *(const float4*)(wsrc);
    float4 w1 = *(const float4*)(wsrc + 4);
    unsigned* d = wbuf + e * 4;
    d[0] = pack_bf16x2(w0.x, w0.y);
    d[1] = pack_bf16x2(w0.z, w0.w);
    d[2] = pack_bf16x2(w1.x, w1.y);
    d[3] = pack_bf16x2(w1.z, w1.w);
  }
}

// ============ CSR build pass 1: bucket-scatter packed edges ============
// packed edge = (dst_local << 17) | src  (dst_local < 125, src < 2^17)
__global__ __launch_bounds__(256) void k_bfill(const int* __restrict__ src,
                                               const int* __restrict__ dst,
                                               int* __restrict__ bucket_cursor,
                                               unsigned* __restrict__ ebuf) {
  __shared__ int lh[NBUCK];
  __shared__ int sub_base[NBUCK];
  __shared__ int cur[NBUCK];
  int t = threadIdx.x;
  for (int b = t; b < NBUCK; b += 256) { lh[b] = 0; cur[b] = 0; }
  __syncthreads();
  int e0 = blockIdx.x * BF_EDGES;
  unsigned pk[16];
  int bk[16];
#pragma unroll
  for (int i = 0; i < 16; ++i) {
    int e = e0 + i * 256 + t;
    bk[i] = -1;
    if (e < N_EDGES) {
      int d = dst[e];
      int b = d / BUCK_NODES;
      int dloc = d - b * BUCK_NODES;
      bk[i] = b;
      pk[i] = ((unsigned)dloc << 17) | (unsigned)src[e];
      atomicAdd(&lh[b], 1);
    }
  }
  __syncthreads();
  for (int b = t; b < NBUCK; b += 256)
    sub_base[b] = (lh[b] > 0) ? atomicAdd(&bucket_cursor[b], lh[b]) : 0;
  __syncthreads();
#pragma unroll
  for (int i = 0; i < 16; ++i) {
    if (bk[i] >= 0) {
      int pos = sub_base[bk[i]] + atomicAdd(&cur[bk[i]], 1);
      if (pos < (bk[i] + 1) * EB_CAP) ebuf[pos] = pk[i];  // +11 sigma guard
    }
  }
}

// ====== CSR build pass 2 + layer-1 (fused): one block per bucket ======
// Builds csr_src/row_start/row_end; aggregates x into LDS (float atomics);
// computes h1 = relu(...), stores bf16 rows (h1b) AND fp8-e4m3 rows (h1f8).
__global__ __launch_bounds__(256) void k_fill2(
    const unsigned* __restrict__ ebuf, const int* __restrict__ bucket_cursor,
    const float* __restrict__ x, const float* __restrict__ W1_rel,
    const float* __restrict__ b1, const float* __restrict__ W1_root,
    int* __restrict__ row_start, int* __restrict__ row_end,
    int* __restrict__ csr_src, unsigned* __restrict__ h1b,
    unsigned short* __restrict__ h1f8) {
  __shared__ int cnt[128];
  __shared__ int start[128];
  __shared__ int partial[4];
  __shared__ float sagg[BUCK_NODES * 4];
  __shared__ float sx[BUCK_NODES * 4];
  __shared__ float sWa[8 * 128];   // SoA: sWa[j*128+f], j<4 = W1_rel col j, j>=4 = W1_root
  __shared__ float sb1[128];
  int t = threadIdx.x;
  int b = blockIdx.x;
  int base = b * EB_CAP;
  int nb = bucket_cursor[b] - base;
  int n0 = b * BUCK_NODES;

  if (t < 128) {
    cnt[t] = 0;
    float4 wr = *(const float4*)(W1_rel + t * 4);
    float4 wo = *(const float4*)(W1_root + t * 4);
    sWa[0 * 128 + t] = wr.x; sWa[1 * 128 + t] = wr.y;
    sWa[2 * 128 + t] = wr.z; sWa[3 * 128 + t] = wr.w;
    sWa[4 * 128 + t] = wo.x; sWa[5 * 128 + t] = wo.y;
    sWa[6 * 128 + t] = wo.z; sWa[7 * 128 + t] = wo.w;
    sb1[t] = b1[t];
  }
  for (int i = t; i < BUCK_NODES * 4; i += 256) sagg[i] = 0.0f;
  __syncthreads();

  for (int i = t; i < nb; i += 256) atomicAdd(&cnt[ebuf[base + i] >> 17], 1);
  __syncthreads();
  if (t < 4) {
    int s = 0;
#pragma unroll
    for (int j = 0; j < 32; ++j) { start[t * 32 + j] = s; s += cnt[t * 32 + j]; }
    partial[t] = s;
  }
  __syncthreads();
  if (t == 0) {
    int s = 0;
#pragma unroll
    for (int j = 0; j < 4; ++j) { int tmp = partial[j]; partial[j] = s; s += tmp; }
  }
  __syncthreads();
  if (t < 4) {
    int off = partial[t];
#pragma unroll
    for (int j = 0; j < 32; ++j) start[t * 32 + j] += off;
  }
  __syncthreads();
  if (t < BUCK_NODES) {
    row_start[n0 + t] = base + start[t];
    cnt[t] = start[t];    // reuse as cursor
    *(float4*)&sx[t * 4] = *(const float4*)(x + (size_t)(n0 + t) * 4);
  }
  __syncthreads();
  for (int i = t; i < nb; i += 256) {
    unsigned e = ebuf[base + i];
    int dloc = e >> 17;
    int s = (int)(e & 0x1FFFFu);
    int p = atomicAdd(&cnt[dloc], 1);
    csr_src[base + p] = s;
    float4 v = *(const float4*)(x + (size_t)s * 4);
    atomicAdd(&sagg[dloc * 4 + 0], v.x);
    atomicAdd(&sagg[dloc * 4 + 1], v.y);
    atomicAdd(&sagg[dloc * 4 + 2], v.z);
    atomicAdd(&sagg[dloc * 4 + 3], v.w);
  }
  __syncthreads();
  if (t < BUCK_NODES) row_end[n0 + t] = base + cnt[t];

  // layer-1 dense: 125 nodes x 64 feature-pairs; dual-format store
  for (int it = t; it < BUCK_NODES * 64; it += 256) {
    int nd = it >> 6;
    int fp = it & 63;
    int f = fp * 2;
    float4 a  = *(float4*)&sagg[nd * 4];
    float4 xv = *(float4*)&sx[nd * 4];
    float v0 = sb1[f]
        + a.x  * sWa[0 * 128 + f] + a.y  * sWa[1 * 128 + f]
        + a.z  * sWa[2 * 128 + f] + a.w  * sWa[3 * 128 + f]
        + xv.x * sWa[4 * 128 + f] + xv.y * sWa[5 * 128 + f]
        + xv.z * sWa[6 * 128 + f] + xv.w * sWa[7 * 128 + f];
    int f1 = f + 1;
    float v1 = sb1[f1]
        + a.x  * sWa[0 * 128 + f1] + a.y  * sWa[1 * 128 + f1]
        + a.z  * sWa[2 * 128 + f1] + a.w  * sWa[3 * 128 + f1]
        + xv.x * sWa[4 * 128 + f1] + xv.y * sWa[5 * 128 + f1]
        + xv.z * sWa[6 * 128 + f1] + xv.w * sWa[7 * 128 + f1];
    float r0 = fmaxf(v0, 0.f), r1 = fmaxf(v1, 0.f);
    size_t idx = (size_t)(n0 + nd) * 64 + fp;
    h1b[idx] = pack_bf16x2(r0, r1);
    h1f8[idx] = (unsigned short)__builtin_amdgcn_cvt_pk_fp8_f32(r0, r1, 0, false);
  }
}

// ============ layer 2 aggregate: pull FP8 h1 rows, one WAVE per node ======
// 2 B/lane per edge (128 B/row) halves gather bytes vs bf16. 4-deep unroll
// (proven in R6; 8-deep thrashed L2 in R7). Output agg2b stays bf16.
__global__ __launch_bounds__(256) void k_pull128(
    const unsigned short* __restrict__ h1f8, const int* __restrict__ row_start,
    const int* __restrict__ row_end, const int* __restrict__ csr_src,
    unsigned* __restrict__ agg2b) {
  int w = (blockIdx.x * 256 + threadIdx.x) >> 6;
  if (w >= N_NODES) return;
  int lane = threadIdx.x & 63;
  int rs = row_start[w], re = row_end[w];
  float ax = 0.f, ay = 0.f;
  for (int chunk = rs; chunk < re; chunk += 64) {
    int nv = min(64, re - chunk);
    int sv = (chunk + lane < re) ? csr_src[chunk + lane] : 0;
    int j = 0;
    for (; j + 4 <= nv; j += 4) {
      int s0 = __shfl(sv, j);
      int s1 = __shfl(sv, j + 1);
      int s2 = __shfl(sv, j + 2);
      int s3 = __shfl(sv, j + 3);
      int u0 = h1f8[(size_t)s0 * 64 + lane];
      int u1 = h1f8[(size_t)s1 * 64 + lane];
      int u2 = h1f8[(size_t)s2 * 64 + lane];
      int u3 = h1f8[(size_t)s3 * 64 + lane];
      f32x2 d0 = __builtin_amdgcn_cvt_pk_f32_fp8(u0, false);
      f32x2 d1 = __builtin_amdgcn_cvt_pk_f32_fp8(u1, false);
      f32x2 d2 = __builtin_amdgcn_cvt_pk_f32_fp8(u2, false);
      f32x2 d3 = __builtin_amdgcn_cvt_pk_f32_fp8(u3, false);
      ax += d0.x + d1.x + d2.x + d3.x;
      ay += d0.y + d1.y + d2.y + d3.y;
    }
    for (; j < nv; ++j) {
      int s0 = __shfl(sv, j);
      int u0 = h1f8[(size_t)s0 * 64 + lane];
      f32x2 d0 = __builtin_amdgcn_cvt_pk_f32_fp8(u0, false);
      ax += d0.x; ay += d0.y;
    }
  }
  agg2b[(size_t)w * 64 + lane] = pack_bf16x2(ax, ay);
}

// ====== layer 2 dense + pool: MFMA GEMM, 32-node waves, global B-frags ======
// B fragments read from fragment-ordered global wbuf (L1/L2-hot, 64 KB) —
// no per-block LDS staging, so occupancy is VGPR-bound, not LDS-bound.
__global__ __launch_bounds__(256) void k_gemm_pool(
    const unsigned* __restrict__ agg2b_u, const unsigned* __restrict__ h1b_u,
    const unsigned* __restrict__ wbuf_u, const float* __restrict__ b2,
    float* __restrict__ gsum) {
  __shared__ float lgs[128];
  int t = threadIdx.x;
  if (t < 128) lgs[t] = 0.0f;
  __syncthreads();

  int lane = t & 63;
  int gw = blockIdx.x * 4 + (t >> 6);
  int lrow = lane & 15;
  int quad = lane >> 4;
  const unsigned short* agg2b = (const unsigned short*)agg2b_u;
  const unsigned short* h1b   = (const unsigned short*)h1b_u;
  const short8* wb = (const short8*)wbuf_u;

  float bias[8];
#pragma unroll
  for (int tt = 0; tt < 8; ++tt) bias[tt] = b2[tt * 16 + lrow];
  float csum[8] = {0.f, 0.f, 0.f, 0.f, 0.f, 0.f, 0.f, 0.f};

  if (gw < NCHUNK32) {
    int mbase = gw * 32;   // N_NODES % 32 == 0: no clamp, no gating

    f32x4 acc[2][8];
#pragma unroll
    for (int mt = 0; mt < 2; ++mt)
#pragma unroll
      for (int tt = 0; tt < 8; ++tt) acc[mt][tt] = (f32x4){0.f, 0.f, 0.f, 0.f};

#pragma unroll
    for (int ks = 0; ks < 8; ++ks) {
      const unsigned short* abase = (ks < 4)
          ? (agg2b + ks * 32 + quad * 8)
          : (h1b + (ks - 4) * 32 + quad * 8);
      short8 afr[2];
#pragma unroll
      for (int mt = 0; mt < 2; ++mt)
        afr[mt] = *(const short8*)(abase + (size_t)(mbase + mt * 16 + lrow) * 128);
      short8 bfr[8];
#pragma unroll
      for (int tt = 0; tt < 8; ++tt) bfr[tt] = wb[(ks * 8 + tt) * 64 + lane];
#pragma unroll
      for (int mt = 0; mt < 2; ++mt)
#pragma unroll
        for (int tt = 0; tt < 8; ++tt)
          acc[mt][tt] = __builtin_amdgcn_mfma_f32_16x16x32_bf16(
              afr[mt], bfr[tt], acc[mt][tt], 0, 0, 0);
    }

#pragma unroll
    for (int mt = 0; mt < 2; ++mt) {
#pragma unroll
      for (int tt = 0; tt < 8; ++tt) {
        f32x4 v = acc[mt][tt];
        float s = fmaxf(v.x + bias[tt], 0.f) + fmaxf(v.y + bias[tt], 0.f)
                + fmaxf(v.z + bias[tt], 0.f) + fmaxf(v.w + bias[tt], 0.f);
        s += __shfl_xor(s, 16);
        s += __shfl_xor(s, 32);
        csum[tt] += s;
      }
    }
  }
  if (lane < 16) {
#pragma unroll
    for (int tt = 0; tt < 8; ++tt) atomicAdd(&lgs[tt * 16 + lane], csum[tt]);
  }
  __syncthreads();
  if (t < 128) atomicAdd(&gsum[t], lgs[t]);
}

// ============ head: out = (gsum/N) @ Wlin.T + blin ============
__global__ void k_final(const float* __restrict__ gsum, const float* __restrict__ Wlin,
                        const float* __restrict__ blin, float* __restrict__ out) {
  int lane = threadIdx.x;  // 64 threads
  float g0 = gsum[lane];
  float g1 = gsum[lane + 64];
  float s0 = g0 * Wlin[lane]       + g1 * Wlin[lane + 64];
  float s1 = g0 * Wlin[128 + lane] + g1 * Wlin[192 + lane];
#pragma unroll
  for (int off = 32; off > 0; off >>= 1) {
    s0 += __shfl_down(s0, off);
    s1 += __shfl_down(s1, off);
  }
  if (lane == 0) {
    const float inv = 1.0f / (float)N_NODES;
    out[0] = s0 * inv + blin[0];
    out[1] = s1 * inv + blin[1];
  }
}

extern "C" void kernel_launch(void* const* d_in, const int* in_sizes, int n_in,
                              void* d_out, int out_size, void* d_ws, size_t ws_size,
                              hipStream_t stream) {
  const float* x       = (const float*)d_in[0];
  const int*   ei      = (const int*)d_in[1];
  const float* W1_rel  = (const float*)d_in[2];
  const float* b1      = (const float*)d_in[3];
  const float* W1_root = (const float*)d_in[4];
  const float* W2_rel  = (const float*)d_in[5];
  const float* b2      = (const float*)d_in[6];
  const float* W2_root = (const float*)d_in[7];
  const float* Wlin    = (const float*)d_in[8];
  const float* blin    = (const float*)d_in[9];
  const int* src = ei;            // edge_index[0]
  const int* dst = ei + N_EDGES;  // edge_index[1]
  float* out = (float*)d_out;

  // workspace layout (bytes):
  //   row_start     @0          : 400,000
  //   row_end       @400,000    : 400,000
  //   bucket_cursor @800,000    : 3,200
  //   gsum          @803,200    : 512
  //   wbuf          @803,712    : 65,536     -> 869,248
  //   csr_src       @869,248    : 8,000,000  -> 8,869,248
  //   ebuf (uint)   @8,869,248  : 8,000,000  -> 16,869,248
  //   h1b  (bf16)   @16,869,248 : 25,600,000 -> 42,469,248
  //   h1f8 (fp8)    @42,469,248 : 12,800,000 -> 55,269,248
  //   agg2b (bf16)  @55,269,248 : 25,600,000 -> 80,869,248
  char* ws = (char*)d_ws;
  int*            row_start     = (int*)(ws);
  int*            row_end       = (int*)(ws + 400000);
  int*            bucket_cursor = (int*)(ws + 800000);
  float*          gsum          = (float*)(ws + 803200);
  unsigned*       wbuf          = (unsigned*)(ws + 803712);
  int*            csr_src       = (int*)(ws + 869248);
  unsigned*       ebuf          = (unsigned*)(ws + 8869248);
  unsigned*       h1b           = (unsigned*)(ws + 16869248);
  unsigned short* h1f8          = (unsigned short*)(ws + 42469248);
  unsigned*       agg2b         = (unsigned*)(ws + 55269248);

  k_init <<<1, 512, 0, stream>>>(bucket_cursor, gsum, W2_rel, W2_root, wbuf);
  k_bfill<<<BF_BLOCKS, 256, 0, stream>>>(src, dst, bucket_cursor, ebuf);
  k_fill2<<<NBUCK, 256, 0, stream>>>(ebuf, bucket_cursor, x, W1_rel, b1, W1_root,
                                     row_start, row_end, csr_src, h1b, h1f8);
  k_pull128<<<(N_NODES * 64 + 255) / 256, 256, 0, stream>>>(h1f8, row_start, row_end,
                                                            csr_src, agg2b);
  k_gemm_pool<<<(NCHUNK32 + 3) / 4, 256, 0, stream>>>(agg2b, h1b, wbuf, b2, gsum);
  k_final<<<1, 64, 0, stream>>>(gsum, Wlin, blin, out);
}

// Round 11
// 246.888 us; speedup vs baseline: 1.4183x; 1.0126x over previous
//
#include <hip/hip_runtime.h>
#include <cstddef>

#define N_NODES 100000
#define N_EDGES 1600000
#define NCHUNK32 3125   // N_NODES / 32, exact
#define BUCK_SHIFT 6
#define BUCK_NODES 64                         // nodes per bucket (pow2: no div)
#define NBUCK 1563                            // ceil(N_NODES / 64)
#define EB_CAP 1536     // mean 1024, sigma ~32 -> +16 sigma
#define BF_EDGES 4096
#define BF_BLOCKS ((N_EDGES + BF_EDGES - 1) / BF_EDGES)   // 391

typedef __attribute__((ext_vector_type(8))) short short8;   // 8 bf16 = 4 VGPRs
typedef __attribute__((ext_vector_type(4))) float f32x4;
typedef __attribute__((ext_vector_type(2))) float f32x2;

__device__ __forceinline__ unsigned pack_bf16x2(float a, float b) {
  unsigned ua = __float_as_uint(a); ua += 0x7FFFu + ((ua >> 16) & 1u);
  unsigned ub = __float_as_uint(b); ub += 0x7FFFu + ((ub >> 16) & 1u);
  return (ua >> 16) | (ub & 0xFFFF0000u);
}

// ====== init: cursors + gsum + fragment-ordered bf16 W2 buffer (global) ====
__global__ __launch_bounds__(512) void k_init(int* __restrict__ bucket_cursor,
                                              float* __restrict__ gsum,
                                              const float* __restrict__ W2_rel,
                                              const float* __restrict__ W2_root,
                                              unsigned* __restrict__ wbuf) {
  int t = threadIdx.x;
  for (int b = t; b < NBUCK; b += 512) bucket_cursor[b] = b * EB_CAP;
  if (t < 128) gsum[t] = 0.0f;
#pragma unroll
  for (int i = 0; i < 8; ++i) {
    int e = t + i * 512;                    // 0..4095
    int L = e & 63, T = (e >> 6) & 7, K0 = e >> 9;
    int f = T * 16 + (L & 15);
    int k0 = K0 * 32 + ((L >> 4) << 3);     // 8-aligned; never crosses 128
    const float* wsrc = (k0 < 128) ? (W2_rel + f * 128 + k0)
                                   : (W2_root + f * 128 + (k0 - 128));
    float4 w0 = *(const float4*)(wsrc);
    float4 w1 = *(const float4*)(wsrc + 4);
    unsigned* d = wbuf + e * 4;
    d[0] = pack_bf16x2(w0.x, w0.y);
    d[1] = pack_bf16x2(w0.z, w0.w);
    d[2] = pack_bf16x2(w1.x, w1.y);
    d[3] = pack_bf16x2(w1.z, w1.w);
  }
}

// ============ CSR build pass 1: bucket-scatter packed edges ============
// packed edge = (dst_local << 17) | src  (dst_local < 64, src < 2^17)
__global__ __launch_bounds__(256) void k_bfill(const int* __restrict__ src,
                                               const int* __restrict__ dst,
                                               int* __restrict__ bucket_cursor,
                                               unsigned* __restrict__ ebuf) {
  __shared__ int lh[NBUCK];
  __shared__ int sub_base[NBUCK];
  __shared__ int cur[NBUCK];
  int t = threadIdx.x;
  for (int b = t; b < NBUCK; b += 256) { lh[b] = 0; cur[b] = 0; }
  __syncthreads();
  int e0 = blockIdx.x * BF_EDGES;
  unsigned pk[16];
  int bk[16];
#pragma unroll
  for (int i = 0; i < 16; ++i) {
    int e = e0 + i * 256 + t;
    bk[i] = -1;
    if (e < N_EDGES) {
      int d = dst[e];
      int b = d >> BUCK_SHIFT;
      bk[i] = b;
      pk[i] = ((unsigned)(d & (BUCK_NODES - 1)) << 17) | (unsigned)src[e];
      atomicAdd(&lh[b], 1);
    }
  }
  __syncthreads();
  for (int b = t; b < NBUCK; b += 256)
    sub_base[b] = (lh[b] > 0) ? atomicAdd(&bucket_cursor[b], lh[b]) : 0;
  __syncthreads();
#pragma unroll
  for (int i = 0; i < 16; ++i) {
    if (bk[i] >= 0) {
      int pos = sub_base[bk[i]] + atomicAdd(&cur[bk[i]], 1);
      if (pos < (bk[i] + 1) * EB_CAP) ebuf[pos] = pk[i];  // +16 sigma guard
    }
  }
}

// ====== CSR build pass 2 + layer-1 (fused): one block per 64-node bucket ====
// Small buckets (64 nodes, ~1K edges) halve the per-block serial chain and
// double grid concurrency vs R10's 125-node buckets (fill2 was latency-bound:
// occupancy 25%, VALUBusy 12%).
__global__ __launch_bounds__(256) void k_fill2(
    const unsigned* __restrict__ ebuf, const int* __restrict__ bucket_cursor,
    const float* __restrict__ x, const float* __restrict__ W1_rel,
    const float* __restrict__ b1, const float* __restrict__ W1_root,
    int* __restrict__ row_start, int* __restrict__ row_end,
    int* __restrict__ csr_src, unsigned* __restrict__ h1b,
    unsigned short* __restrict__ h1f8) {
  __shared__ int cnt[BUCK_NODES];
  __shared__ int start[BUCK_NODES];
  __shared__ float sagg[BUCK_NODES * 4];
  __shared__ float sx[BUCK_NODES * 4];
  __shared__ float sWa[8 * 128];   // SoA: sWa[j*128+f], j<4 = W1_rel col j, j>=4 = W1_root
  __shared__ float sb1[128];
  int t = threadIdx.x;
  int b = blockIdx.x;
  int base = b * EB_CAP;
  int nb = bucket_cursor[b] - base;
  if (nb > EB_CAP) nb = EB_CAP;
  int n0 = b << BUCK_SHIFT;

  if (t < 128) {
    float4 wr = *(const float4*)(W1_rel + t * 4);
    float4 wo = *(const float4*)(W1_root + t * 4);
    sWa[0 * 128 + t] = wr.x; sWa[1 * 128 + t] = wr.y;
    sWa[2 * 128 + t] = wr.z; sWa[3 * 128 + t] = wr.w;
    sWa[4 * 128 + t] = wo.x; sWa[5 * 128 + t] = wo.y;
    sWa[6 * 128 + t] = wo.z; sWa[7 * 128 + t] = wo.w;
    sb1[t] = b1[t];
  }
  sagg[t] = 0.0f;                       // 256 == BUCK_NODES*4, exact
  if (t < BUCK_NODES) {
    cnt[t] = 0;
    float4 xv = make_float4(0.f, 0.f, 0.f, 0.f);
    if (n0 + t < N_NODES) xv = *(const float4*)(x + (size_t)(n0 + t) * 4);
    *(float4*)&sx[t * 4] = xv;
  }
  __syncthreads();

  // per-node degree histogram
  for (int i = t; i < nb; i += 256) atomicAdd(&cnt[ebuf[base + i] >> 17], 1);
  __syncthreads();
  // exclusive scan of 64 (thread 0; trivial)
  if (t == 0) {
    int s = 0;
#pragma unroll
    for (int j = 0; j < BUCK_NODES; ++j) { start[j] = s; s += cnt[j]; }
  }
  __syncthreads();
  if (t < BUCK_NODES) {
    if (n0 + t < N_NODES) row_start[n0 + t] = base + start[t];
    cnt[t] = start[t];    // reuse as cursor
  }
  __syncthreads();
  // scatter csr + aggregate x into LDS in one pass
  for (int i = t; i < nb; i += 256) {
    unsigned e = ebuf[base + i];
    int dloc = e >> 17;
    int s = (int)(e & 0x1FFFFu);
    int p = atomicAdd(&cnt[dloc], 1);
    csr_src[base + p] = s;
    float4 v = *(const float4*)(x + (size_t)s * 4);
    atomicAdd(&sagg[dloc * 4 + 0], v.x);
    atomicAdd(&sagg[dloc * 4 + 1], v.y);
    atomicAdd(&sagg[dloc * 4 + 2], v.z);
    atomicAdd(&sagg[dloc * 4 + 3], v.w);
  }
  __syncthreads();
  if (t < BUCK_NODES && n0 + t < N_NODES) row_end[n0 + t] = base + cnt[t];

  // layer-1 dense: 64 nodes x 64 feature-pairs = 4096; dual-format store
  for (int it = t; it < BUCK_NODES * 64; it += 256) {
    int nd = it >> 6;
    if (n0 + nd >= N_NODES) break;
    int fp = it & 63;
    int f = fp * 2;
    float4 a  = *(float4*)&sagg[nd * 4];
    float4 xv = *(float4*)&sx[nd * 4];
    float v0 = sb1[f]
        + a.x  * sWa[0 * 128 + f] + a.y  * sWa[1 * 128 + f]
        + a.z  * sWa[2 * 128 + f] + a.w  * sWa[3 * 128 + f]
        + xv.x * sWa[4 * 128 + f] + xv.y * sWa[5 * 128 + f]
        + xv.z * sWa[6 * 128 + f] + xv.w * sWa[7 * 128 + f];
    int f1 = f + 1;
    float v1 = sb1[f1]
        + a.x  * sWa[0 * 128 + f1] + a.y  * sWa[1 * 128 + f1]
        + a.z  * sWa[2 * 128 + f1] + a.w  * sWa[3 * 128 + f1]
        + xv.x * sWa[4 * 128 + f1] + xv.y * sWa[5 * 128 + f1]
        + xv.z * sWa[6 * 128 + f1] + xv.w * sWa[7 * 128 + f1];
    float r0 = fmaxf(v0, 0.f), r1 = fmaxf(v1, 0.f);
    size_t idx = (size_t)(n0 + nd) * 64 + fp;
    h1b[idx] = pack_bf16x2(r0, r1);
    h1f8[idx] = (unsigned short)__builtin_amdgcn_cvt_pk_fp8_f32(r0, r1, 0, false);
  }
}

// ============ layer 2 aggregate: pull FP8 h1 rows, one WAVE per node ======
__global__ __launch_bounds__(256) void k_pull128(
    const unsigned short* __restrict__ h1f8, const int* __restrict__ row_start,
    const int* __restrict__ row_end, const int* __restrict__ csr_src,
    unsigned* __restrict__ agg2b) {
  int w = (blockIdx.x * 256 + threadIdx.x) >> 6;
  if (w >= N_NODES) return;
  int lane = threadIdx.x & 63;
  int rs = row_start[w], re = row_end[w];
  float ax = 0.f, ay = 0.f;
  for (int chunk = rs; chunk < re; chunk += 64) {
    int nv = min(64, re - chunk);
    int sv = (chunk + lane < re) ? csr_src[chunk + lane] : 0;
    int j = 0;
    for (; j + 4 <= nv; j += 4) {
      int s0 = __shfl(sv, j);
      int s1 = __shfl(sv, j + 1);
      int s2 = __shfl(sv, j + 2);
      int s3 = __shfl(sv, j + 3);
      int u0 = h1f8[(size_t)s0 * 64 + lane];
      int u1 = h1f8[(size_t)s1 * 64 + lane];
      int u2 = h1f8[(size_t)s2 * 64 + lane];
      int u3 = h1f8[(size_t)s3 * 64 + lane];
      f32x2 d0 = __builtin_amdgcn_cvt_pk_f32_fp8(u0, false);
      f32x2 d1 = __builtin_amdgcn_cvt_pk_f32_fp8(u1, false);
      f32x2 d2 = __builtin_amdgcn_cvt_pk_f32_fp8(u2, false);
      f32x2 d3 = __builtin_amdgcn_cvt_pk_f32_fp8(u3, false);
      ax += d0.x + d1.x + d2.x + d3.x;
      ay += d0.y + d1.y + d2.y + d3.y;
    }
    for (; j < nv; ++j) {
      int s0 = __shfl(sv, j);
      int u0 = h1f8[(size_t)s0 * 64 + lane];
      f32x2 d0 = __builtin_amdgcn_cvt_pk_f32_fp8(u0, false);
      ax += d0.x; ay += d0.y;
    }
  }
  agg2b[(size_t)w * 64 + lane] = pack_bf16x2(ax, ay);
}

// ====== layer 2 dense + pool: MFMA GEMM, 32-node waves, global B-frags ======
__global__ __launch_bounds__(256) void k_gemm_pool(
    const unsigned* __restrict__ agg2b_u, const unsigned* __restrict__ h1b_u,
    const unsigned* __restrict__ wbuf_u, const float* __restrict__ b2,
    float* __restrict__ gsum) {
  __shared__ float lgs[128];
  int t = threadIdx.x;
  if (t < 128) lgs[t] = 0.0f;
  __syncthreads();

  int lane = t & 63;
  int gw = blockIdx.x * 4 + (t >> 6);
  int lrow = lane & 15;
  int quad = lane >> 4;
  const unsigned short* agg2b = (const unsigned short*)agg2b_u;
  const unsigned short* h1b   = (const unsigned short*)h1b_u;
  const short8* wb = (const short8*)wbuf_u;

  float bias[8];
#pragma unroll
  for (int tt = 0; tt < 8; ++tt) bias[tt] = b2[tt * 16 + lrow];
  float csum[8] = {0.f, 0.f, 0.f, 0.f, 0.f, 0.f, 0.f, 0.f};

  if (gw < NCHUNK32) {
    int mbase = gw * 32;   // N_NODES % 32 == 0: no clamp, no gating

    f32x4 acc[2][8];
#pragma unroll
    for (int mt = 0; mt < 2; ++mt)
#pragma unroll
      for (int tt = 0; tt < 8; ++tt) acc[mt][tt] = (f32x4){0.f, 0.f, 0.f, 0.f};

#pragma unroll
    for (int ks = 0; ks < 8; ++ks) {
      const unsigned short* abase = (ks < 4)
          ? (agg2b + ks * 32 + quad * 8)
          : (h1b + (ks - 4) * 32 + quad * 8);
      short8 afr[2];
#pragma unroll
      for (int mt = 0; mt < 2; ++mt)
        afr[mt] = *(const short8*)(abase + (size_t)(mbase + mt * 16 + lrow) * 128);
      short8 bfr[8];
#pragma unroll
      for (int tt = 0; tt < 8; ++tt) bfr[tt] = wb[(ks * 8 + tt) * 64 + lane];
#pragma unroll
      for (int mt = 0; mt < 2; ++mt)
#pragma unroll
        for (int tt = 0; tt < 8; ++tt)
          acc[mt][tt] = __builtin_amdgcn_mfma_f32_16x16x32_bf16(
              afr[mt], bfr[tt], acc[mt][tt], 0, 0, 0);
    }

#pragma unroll
    for (int mt = 0; mt < 2; ++mt) {
#pragma unroll
      for (int tt = 0; tt < 8; ++tt) {
        f32x4 v = acc[mt][tt];
        float s = fmaxf(v.x + bias[tt], 0.f) + fmaxf(v.y + bias[tt], 0.f)
                + fmaxf(v.z + bias[tt], 0.f) + fmaxf(v.w + bias[tt], 0.f);
        s += __shfl_xor(s, 16);
        s += __shfl_xor(s, 32);
        csum[tt] += s;
      }
    }
  }
  if (lane < 16) {
#pragma unroll
    for (int tt = 0; tt < 8; ++tt) atomicAdd(&lgs[tt * 16 + lane], csum[tt]);
  }
  __syncthreads();
  if (t < 128) atomicAdd(&gsum[t], lgs[t]);
}

// ============ head: out = (gsum/N) @ Wlin.T + blin ============
__global__ void k_final(const float* __restrict__ gsum, const float* __restrict__ Wlin,
                        const float* __restrict__ blin, float* __restrict__ out) {
  int lane = threadIdx.x;  // 64 threads
  float g0 = gsum[lane];
  float g1 = gsum[lane + 64];
  float s0 = g0 * Wlin[lane]       + g1 * Wlin[lane + 64];
  float s1 = g0 * Wlin[128 + lane] + g1 * Wlin[192 + lane];
#pragma unroll
  for (int off = 32; off > 0; off >>= 1) {
    s0 += __shfl_down(s0, off);
    s1 += __shfl_down(s1, off);
  }
  if (lane == 0) {
    const float inv = 1.0f / (float)N_NODES;
    out[0] = s0 * inv + blin[0];
    out[1] = s1 * inv + blin[1];
  }
}

extern "C" void kernel_launch(void* const* d_in, const int* in_sizes, int n_in,
                              void* d_out, int out_size, void* d_ws, size_t ws_size,
                              hipStream_t stream) {
  const float* x       = (const float*)d_in[0];
  const int*   ei      = (const int*)d_in[1];
  const float* W1_rel  = (const float*)d_in[2];
  const float* b1      = (const float*)d_in[3];
  const float* W1_root = (const float*)d_in[4];
  const float* W2_rel  = (const float*)d_in[5];
  const float* b2      = (const float*)d_in[6];
  const float* W2_root = (const float*)d_in[7];
  const float* Wlin    = (const float*)d_in[8];
  const float* blin    = (const float*)d_in[9];
  const int* src = ei;            // edge_index[0]
  const int* dst = ei + N_EDGES;  // edge_index[1]
  float* out = (float*)d_out;

  // workspace layout (bytes):
  //   row_start     @0          : 400,000
  //   row_end       @400,000    : 400,000
  //   bucket_cursor @800,000    : 8,192      (NBUCK=1563 ints, padded)
  //   gsum          @808,192    : 512
  //   wbuf          @808,704    : 65,536     -> 874,240
  //   csr_src       @874,240    : 9,603,072  -> 10,477,312   (NBUCK*EB_CAP*4)
  //   ebuf (uint)   @10,477,312 : 9,603,072  -> 20,080,384
  //   h1b  (bf16)   @20,080,384 : 25,600,000 -> 45,680,384
  //   h1f8 (fp8)    @45,680,384 : 12,800,000 -> 58,480,384
  //   agg2b (bf16)  @58,480,384 : 25,600,000 -> 84,080,384
  char* ws = (char*)d_ws;
  int*            row_start     = (int*)(ws);
  int*            row_end       = (int*)(ws + 400000);
  int*            bucket_cursor = (int*)(ws + 800000);
  float*          gsum          = (float*)(ws + 808192);
  unsigned*       wbuf          = (unsigned*)(ws + 808704);
  int*            csr_src       = (int*)(ws + 874240);
  unsigned*       ebuf          = (unsigned*)(ws + 10477312);
  unsigned*       h1b           = (unsigned*)(ws + 20080384);
  unsigned short* h1f8          = (unsigned short*)(ws + 45680384);
  unsigned*       agg2b         = (unsigned*)(ws + 58480384);

  k_init <<<1, 512, 0, stream>>>(bucket_cursor, gsum, W2_rel, W2_root, wbuf);
  k_bfill<<<BF_BLOCKS, 256, 0, stream>>>(src, dst, bucket_cursor, ebuf);
  k_fill2<<<NBUCK, 256, 0, stream>>>(ebuf, bucket_cursor, x, W1_rel, b1, W1_root,
                                     row_start, row_end, csr_src, h1b, h1f8);
  k_pull128<<<(N_NODES * 64 + 255) / 256, 256, 0, stream>>>(h1f8, row_start, row_end,
                                                            csr_src, agg2b);
  k_gemm_pool<<<(NCHUNK32 + 3) / 4, 256, 0, stream>>>(agg2b, h1b, wbuf, b2, gsum);
  k_final<<<1, 64, 0, stream>>>(gsum, Wlin, blin, out);
}

// Round 12
// 212.565 us; speedup vs baseline: 1.6473x; 1.1615x over previous
//
#include <hip/hip_runtime.h>
#include <cstddef>

#define N_NODES 100000
#define N_EDGES 1600000
#define NCHUNK32 3125   // N_NODES / 32, exact
#define BUCK_SHIFT 6
#define BUCK_NODES 64                         // nodes per bucket (pow2: no div)
#define NBUCK 1563                            // ceil(N_NODES / 64)
#define EB_CAP 1536     // mean 1024, sigma ~32 -> +16 sigma
#define BF_EDGES 8192
#define BF_BLOCKS ((N_EDGES + BF_EDGES - 1) / BF_EDGES)   // 196

typedef __attribute__((ext_vector_type(8))) short short8;   // 8 bf16 = 4 VGPRs
typedef __attribute__((ext_vector_type(4))) float f32x4;
typedef __attribute__((ext_vector_type(2))) float f32x2;

__device__ __forceinline__ unsigned pack_bf16x2(float a, float b) {
  unsigned ua = __float_as_uint(a); ua += 0x7FFFu + ((ua >> 16) & 1u);
  unsigned ub = __float_as_uint(b); ub += 0x7FFFu + ((ub >> 16) & 1u);
  return (ua >> 16) | (ub & 0xFFFF0000u);
}

// ====== init: cursors + gsum + fragment-ordered bf16 W2 buffer (global) ====
__global__ __launch_bounds__(512) void k_init(int* __restrict__ bucket_cursor,
                                              float* __restrict__ gsum,
                                              const float* __restrict__ W2_rel,
                                              const float* __restrict__ W2_root,
                                              unsigned* __restrict__ wbuf) {
  int t = threadIdx.x;
  for (int b = t; b < NBUCK; b += 512) bucket_cursor[b] = b * EB_CAP;
  if (t < 128) gsum[t] = 0.0f;
#pragma unroll
  for (int i = 0; i < 8; ++i) {
    int e = t + i * 512;                    // 0..4095
    int L = e & 63, T = (e >> 6) & 7, K0 = e >> 9;
    int f = T * 16 + (L & 15);
    int k0 = K0 * 32 + ((L >> 4) << 3);     // 8-aligned; never crosses 128
    const float* wsrc = (k0 < 128) ? (W2_rel + f * 128 + k0)
                                   : (W2_root + f * 128 + (k0 - 128));
    float4 w0 = *(const float4*)(wsrc);
    float4 w1 = *(const float4*)(wsrc + 4);
    unsigned* d = wbuf + e * 4;
    d[0] = pack_bf16x2(w0.x, w0.y);
    d[1] = pack_bf16x2(w0.z, w0.w);
    d[2] = pack_bf16x2(w1.x, w1.y);
    d[3] = pack_bf16x2(w1.z, w1.w);
  }
}

// ============ CSR build pass 1: bucket-scatter packed edges ============
// packed edge = (dst_local << 17) | src. 8192 edges/block (512 thr) halves the
// contested sub_base global atomics vs 4096/block.
__global__ __launch_bounds__(512) void k_bfill(const int* __restrict__ src,
                                               const int* __restrict__ dst,
                                               int* __restrict__ bucket_cursor,
                                               unsigned* __restrict__ ebuf) {
  __shared__ int lh[NBUCK];
  __shared__ int sub_base[NBUCK];
  __shared__ int cur[NBUCK];
  int t = threadIdx.x;
  for (int b = t; b < NBUCK; b += 512) { lh[b] = 0; cur[b] = 0; }
  __syncthreads();
  int e0 = blockIdx.x * BF_EDGES;
  unsigned pk[16];
  int bk[16];
#pragma unroll
  for (int i = 0; i < 16; ++i) {
    int e = e0 + i * 512 + t;
    bk[i] = -1;
    if (e < N_EDGES) {
      int d = dst[e];
      int b = d >> BUCK_SHIFT;
      bk[i] = b;
      pk[i] = ((unsigned)(d & (BUCK_NODES - 1)) << 17) | (unsigned)src[e];
      atomicAdd(&lh[b], 1);
    }
  }
  __syncthreads();
  for (int b = t; b < NBUCK; b += 512)
    sub_base[b] = (lh[b] > 0) ? atomicAdd(&bucket_cursor[b], lh[b]) : 0;
  __syncthreads();
#pragma unroll
  for (int i = 0; i < 16; ++i) {
    if (bk[i] >= 0) {
      int pos = sub_base[bk[i]] + atomicAdd(&cur[bk[i]], 1);
      if (pos < (bk[i] + 1) * EB_CAP) ebuf[pos] = pk[i];  // +16 sigma guard
    }
  }
}

// ====== CSR build pass 2 + layer-1 (fused): one block per 64-node bucket ====
// R12: wave-shfl scan (was thread-0 serial); scatter and x-gather split
// (cooperative 4-thread/node gather, no LDS atomics); h1 stored fp8 ONLY.
__global__ __launch_bounds__(256) void k_fill2(
    const unsigned* __restrict__ ebuf, const int* __restrict__ bucket_cursor,
    const float* __restrict__ x, const float* __restrict__ W1_rel,
    const float* __restrict__ b1, const float* __restrict__ W1_root,
    int* __restrict__ row_start, int* __restrict__ row_end,
    int* __restrict__ csr_src, unsigned short* __restrict__ h1f8) {
  __shared__ int cnt[BUCK_NODES];
  __shared__ int start[BUCK_NODES];
  __shared__ float sagg[BUCK_NODES * 4];
  __shared__ float sx[BUCK_NODES * 4];
  __shared__ float sWa[8 * 128];   // SoA: sWa[j*128+f], j<4 = W1_rel col j, j>=4 = W1_root
  __shared__ float sb1[128];
  int t = threadIdx.x;
  int b = blockIdx.x;
  int base = b * EB_CAP;
  int nb = bucket_cursor[b] - base;
  if (nb > EB_CAP) nb = EB_CAP;
  int n0 = b << BUCK_SHIFT;

  if (t < 128) {
    float4 wr = *(const float4*)(W1_rel + t * 4);
    float4 wo = *(const float4*)(W1_root + t * 4);
    sWa[0 * 128 + t] = wr.x; sWa[1 * 128 + t] = wr.y;
    sWa[2 * 128 + t] = wr.z; sWa[3 * 128 + t] = wr.w;
    sWa[4 * 128 + t] = wo.x; sWa[5 * 128 + t] = wo.y;
    sWa[6 * 128 + t] = wo.z; sWa[7 * 128 + t] = wo.w;
    sb1[t] = b1[t];
  }
  if (t < BUCK_NODES) {
    cnt[t] = 0;
    float4 xv = make_float4(0.f, 0.f, 0.f, 0.f);
    if (n0 + t < N_NODES) xv = *(const float4*)(x + (size_t)(n0 + t) * 4);
    *(float4*)&sx[t * 4] = xv;
  }
  __syncthreads();

  // per-node degree histogram
  for (int i = t; i < nb; i += 256) atomicAdd(&cnt[ebuf[base + i] >> 17], 1);
  __syncthreads();
  // exclusive scan of 64 via wave-0 shfl (6 steps vs 64 serial LDS RTs)
  if (t < 64) {
    int v = cnt[t];
    int incl = v;
#pragma unroll
    for (int off = 1; off < 64; off <<= 1) {
      int nvv = __shfl_up(incl, off);
      if (t >= off) incl += nvv;
    }
    int excl = incl - v;
    start[t] = excl;
    cnt[t] = excl;          // becomes fill cursor
    if (n0 + t < N_NODES) row_start[n0 + t] = base + excl;
  }
  __syncthreads();
  // scatter csr (no x work: keeps the atomic chain short)
  for (int i = t; i < nb; i += 256) {
    unsigned e = ebuf[base + i];
    int p = atomicAdd(&cnt[e >> 17], 1);
    csr_src[base + p] = (int)(e & 0x1FFFFu);
  }
  __syncthreads();   // drains stores (vmcnt(0)): csr_src visible block-wide
  // cooperative per-node x aggregation: 4 threads/node, independent loads
  {
    int nd = t >> 2, sub = t & 3;
    int rs = base + start[nd];
    int re = base + cnt[nd];
    float4 acc = make_float4(0.f, 0.f, 0.f, 0.f);
    for (int i = rs + sub; i < re; i += 4) {
      int s = csr_src[i];
      float4 v = *(const float4*)(x + (size_t)s * 4);
      acc.x += v.x; acc.y += v.y; acc.z += v.z; acc.w += v.w;
    }
#pragma unroll
    for (int off = 1; off < 4; off <<= 1) {
      acc.x += __shfl_xor(acc.x, off);
      acc.y += __shfl_xor(acc.y, off);
      acc.z += __shfl_xor(acc.z, off);
      acc.w += __shfl_xor(acc.w, off);
    }
    if (sub == 0) *(float4*)&sagg[nd * 4] = acc;
    if (t < 64 && n0 + t < N_NODES) row_end[n0 + t] = base + cnt[t];
  }
  __syncthreads();

  // layer-1 dense: 64 nodes x 64 feature-pairs; fp8 store only
  for (int it = t; it < BUCK_NODES * 64; it += 256) {
    int nd = it >> 6;
    if (n0 + nd >= N_NODES) break;
    int fp = it & 63;
    int f = fp * 2;
    float4 a  = *(float4*)&sagg[nd * 4];
    float4 xv = *(float4*)&sx[nd * 4];
    float v0 = sb1[f]
        + a.x  * sWa[0 * 128 + f] + a.y  * sWa[1 * 128 + f]
        + a.z  * sWa[2 * 128 + f] + a.w  * sWa[3 * 128 + f]
        + xv.x * sWa[4 * 128 + f] + xv.y * sWa[5 * 128 + f]
        + xv.z * sWa[6 * 128 + f] + xv.w * sWa[7 * 128 + f];
    int f1 = f + 1;
    float v1 = sb1[f1]
        + a.x  * sWa[0 * 128 + f1] + a.y  * sWa[1 * 128 + f1]
        + a.z  * sWa[2 * 128 + f1] + a.w  * sWa[3 * 128 + f1]
        + xv.x * sWa[4 * 128 + f1] + xv.y * sWa[5 * 128 + f1]
        + xv.z * sWa[6 * 128 + f1] + xv.w * sWa[7 * 128 + f1];
    float r0 = fmaxf(v0, 0.f), r1 = fmaxf(v1, 0.f);
    h1f8[(size_t)(n0 + nd) * 64 + fp] =
        (unsigned short)__builtin_amdgcn_cvt_pk_fp8_f32(r0, r1, 0, false);
  }
}

// ============ layer 2 aggregate: pull FP8 h1 rows, one WAVE per node ======
__global__ __launch_bounds__(256) void k_pull128(
    const unsigned short* __restrict__ h1f8, const int* __restrict__ row_start,
    const int* __restrict__ row_end, const int* __restrict__ csr_src,
    unsigned* __restrict__ agg2b) {
  int w = (blockIdx.x * 256 + threadIdx.x) >> 6;
  if (w >= N_NODES) return;
  int lane = threadIdx.x & 63;
  int rs = row_start[w], re = row_end[w];
  float ax = 0.f, ay = 0.f;
  for (int chunk = rs; chunk < re; chunk += 64) {
    int nv = min(64, re - chunk);
    int sv = (chunk + lane < re) ? csr_src[chunk + lane] : 0;
    int j = 0;
    for (; j + 4 <= nv; j += 4) {
      int s0 = __shfl(sv, j);
      int s1 = __shfl(sv, j + 1);
      int s2 = __shfl(sv, j + 2);
      int s3 = __shfl(sv, j + 3);
      int u0 = h1f8[(size_t)s0 * 64 + lane];
      int u1 = h1f8[(size_t)s1 * 64 + lane];
      int u2 = h1f8[(size_t)s2 * 64 + lane];
      int u3 = h1f8[(size_t)s3 * 64 + lane];
      f32x2 d0 = __builtin_amdgcn_cvt_pk_f32_fp8(u0, false);
      f32x2 d1 = __builtin_amdgcn_cvt_pk_f32_fp8(u1, false);
      f32x2 d2 = __builtin_amdgcn_cvt_pk_f32_fp8(u2, false);
      f32x2 d3 = __builtin_amdgcn_cvt_pk_f32_fp8(u3, false);
      ax += d0.x + d1.x + d2.x + d3.x;
      ay += d0.y + d1.y + d2.y + d3.y;
    }
    for (; j < nv; ++j) {
      int s0 = __shfl(sv, j);
      int u0 = h1f8[(size_t)s0 * 64 + lane];
      f32x2 d0 = __builtin_amdgcn_cvt_pk_f32_fp8(u0, false);
      ax += d0.x; ay += d0.y;
    }
  }
  agg2b[(size_t)w * 64 + lane] = pack_bf16x2(ax, ay);
}

// ====== layer 2 dense + pool: MFMA GEMM, 32-node waves ======
// A: ks 0..3 from bf16 agg2b rows; ks 4..7 decoded in-register from fp8 h1f8
// (fp8 exact in bf16). B frags from fragment-ordered global wbuf.
__global__ __launch_bounds__(256) void k_gemm_pool(
    const unsigned* __restrict__ agg2b_u, const unsigned short* __restrict__ h1f8,
    const unsigned* __restrict__ wbuf_u, const float* __restrict__ b2,
    float* __restrict__ gsum) {
  __shared__ float lgs[128];
  int t = threadIdx.x;
  if (t < 128) lgs[t] = 0.0f;
  __syncthreads();

  int lane = t & 63;
  int gw = blockIdx.x * 4 + (t >> 6);
  int lrow = lane & 15;
  int quad = lane >> 4;
  const unsigned short* agg2b = (const unsigned short*)agg2b_u;
  const unsigned char* h8 = (const unsigned char*)h1f8;
  const short8* wb = (const short8*)wbuf_u;

  float bias[8];
#pragma unroll
  for (int tt = 0; tt < 8; ++tt) bias[tt] = b2[tt * 16 + lrow];
  float csum[8] = {0.f, 0.f, 0.f, 0.f, 0.f, 0.f, 0.f, 0.f};

  if (gw < NCHUNK32) {
    int mbase = gw * 32;   // N_NODES % 32 == 0

    f32x4 acc[2][8];
#pragma unroll
    for (int mt = 0; mt < 2; ++mt)
#pragma unroll
      for (int tt = 0; tt < 8; ++tt) acc[mt][tt] = (f32x4){0.f, 0.f, 0.f, 0.f};

    // ks 0..3: aggregated half (bf16 rows)
#pragma unroll
    for (int ks = 0; ks < 4; ++ks) {
      const unsigned short* abase = agg2b + ks * 32 + quad * 8;
      short8 afr[2];
#pragma unroll
      for (int mt = 0; mt < 2; ++mt)
        afr[mt] = *(const short8*)(abase + (size_t)(mbase + mt * 16 + lrow) * 128);
      short8 bfr[8];
#pragma unroll
      for (int tt = 0; tt < 8; ++tt) bfr[tt] = wb[(ks * 8 + tt) * 64 + lane];
#pragma unroll
      for (int mt = 0; mt < 2; ++mt)
#pragma unroll
        for (int tt = 0; tt < 8; ++tt)
          acc[mt][tt] = __builtin_amdgcn_mfma_f32_16x16x32_bf16(
              afr[mt], bfr[tt], acc[mt][tt], 0, 0, 0);
    }
    // ks 4..7: root half, fp8 -> bf16 in-register
#pragma unroll
    for (int ks = 4; ks < 8; ++ks) {
      short8 afr[2];
#pragma unroll
      for (int mt = 0; mt < 2; ++mt) {
        const uint2* ap = (const uint2*)(h8 + (size_t)(mbase + mt * 16 + lrow) * 128
                                         + (ks - 4) * 32 + quad * 8);
        uint2 u = *ap;
        f32x2 a0 = __builtin_amdgcn_cvt_pk_f32_fp8((int)u.x, false);
        f32x2 a1 = __builtin_amdgcn_cvt_pk_f32_fp8((int)u.x, true);
        f32x2 a2 = __builtin_amdgcn_cvt_pk_f32_fp8((int)u.y, false);
        f32x2 a3 = __builtin_amdgcn_cvt_pk_f32_fp8((int)u.y, true);
        unsigned q0 = pack_bf16x2(a0.x, a0.y);
        unsigned q1 = pack_bf16x2(a1.x, a1.y);
        unsigned q2 = pack_bf16x2(a2.x, a2.y);
        unsigned q3 = pack_bf16x2(a3.x, a3.y);
        unsigned q[4] = {q0, q1, q2, q3};
        afr[mt] = *(short8*)q;
      }
      short8 bfr[8];
#pragma unroll
      for (int tt = 0; tt < 8; ++tt) bfr[tt] = wb[(ks * 8 + tt) * 64 + lane];
#pragma unroll
      for (int mt = 0; mt < 2; ++mt)
#pragma unroll
        for (int tt = 0; tt < 8; ++tt)
          acc[mt][tt] = __builtin_amdgcn_mfma_f32_16x16x32_bf16(
              afr[mt], bfr[tt], acc[mt][tt], 0, 0, 0);
    }

#pragma unroll
    for (int mt = 0; mt < 2; ++mt) {
#pragma unroll
      for (int tt = 0; tt < 8; ++tt) {
        f32x4 v = acc[mt][tt];
        float s = fmaxf(v.x + bias[tt], 0.f) + fmaxf(v.y + bias[tt], 0.f)
                + fmaxf(v.z + bias[tt], 0.f) + fmaxf(v.w + bias[tt], 0.f);
        s += __shfl_xor(s, 16);
        s += __shfl_xor(s, 32);
        csum[tt] += s;
      }
    }
  }
  if (lane < 16) {
#pragma unroll
    for (int tt = 0; tt < 8; ++tt) atomicAdd(&lgs[tt * 16 + lane], csum[tt]);
  }
  __syncthreads();
  if (t < 128) atomicAdd(&gsum[t], lgs[t]);
}

// ============ head: out = (gsum/N) @ Wlin.T + blin ============
__global__ void k_final(const float* __restrict__ gsum, const float* __restrict__ Wlin,
                        const float* __restrict__ blin, float* __restrict__ out) {
  int lane = threadIdx.x;  // 64 threads
  float g0 = gsum[lane];
  float g1 = gsum[lane + 64];
  float s0 = g0 * Wlin[lane]       + g1 * Wlin[lane + 64];
  float s1 = g0 * Wlin[128 + lane] + g1 * Wlin[192 + lane];
#pragma unroll
  for (int off = 32; off > 0; off >>= 1) {
    s0 += __shfl_down(s0, off);
    s1 += __shfl_down(s1, off);
  }
  if (lane == 0) {
    const float inv = 1.0f / (float)N_NODES;
    out[0] = s0 * inv + blin[0];
    out[1] = s1 * inv + blin[1];
  }
}

extern "C" void kernel_launch(void* const* d_in, const int* in_sizes, int n_in,
                              void* d_out, int out_size, void* d_ws, size_t ws_size,
                              hipStream_t stream) {
  const float* x       = (const float*)d_in[0];
  const int*   ei      = (const int*)d_in[1];
  const float* W1_rel  = (const float*)d_in[2];
  const float* b1      = (const float*)d_in[3];
  const float* W1_root = (const float*)d_in[4];
  const float* W2_rel  = (const float*)d_in[5];
  const float* b2      = (const float*)d_in[6];
  const float* W2_root = (const float*)d_in[7];
  const float* Wlin    = (const float*)d_in[8];
  const float* blin    = (const float*)d_in[9];
  const int* src = ei;            // edge_index[0]
  const int* dst = ei + N_EDGES;  // edge_index[1]
  float* out = (float*)d_out;

  // workspace layout (bytes):
  //   row_start     @0          : 400,000
  //   row_end       @400,000    : 400,000
  //   bucket_cursor @800,000    : 8,192
  //   gsum          @808,192    : 512
  //   wbuf          @808,704    : 65,536     -> 874,240
  //   csr_src       @874,240    : 9,603,072  -> 10,477,312   (NBUCK*EB_CAP*4)
  //   ebuf (uint)   @10,477,312 : 9,603,072  -> 20,080,384
  //   h1f8 (fp8)    @20,080,384 : 12,800,000 -> 32,880,384
  //   agg2b (bf16)  @32,880,384 : 25,600,000 -> 58,480,384
  char* ws = (char*)d_ws;
  int*            row_start     = (int*)(ws);
  int*            row_end       = (int*)(ws + 400000);
  int*            bucket_cursor = (int*)(ws + 800000);
  float*          gsum          = (float*)(ws + 808192);
  unsigned*       wbuf          = (unsigned*)(ws + 808704);
  int*            csr_src       = (int*)(ws + 874240);
  unsigned*       ebuf          = (unsigned*)(ws + 10477312);
  unsigned short* h1f8          = (unsigned short*)(ws + 20080384);
  unsigned*       agg2b         = (unsigned*)(ws + 32880384);

  k_init <<<1, 512, 0, stream>>>(bucket_cursor, gsum, W2_rel, W2_root, wbuf);
  k_bfill<<<BF_BLOCKS, 512, 0, stream>>>(src, dst, bucket_cursor, ebuf);
  k_fill2<<<NBUCK, 256, 0, stream>>>(ebuf, bucket_cursor, x, W1_rel, b1, W1_root,
                                     row_start, row_end, csr_src, h1f8);
  k_pull128<<<(N_NODES * 64 + 255) / 256, 256, 0, stream>>>(h1f8, row_start, row_end,
                                                            csr_src, agg2b);
  k_gemm_pool<<<(NCHUNK32 + 3) / 4, 256, 0, stream>>>(agg2b, h1f8, wbuf, b2, gsum);
  k_final<<<1, 64, 0, stream>>>(gsum, Wlin, blin, out);
}